// Round 2
// baseline (296.177 us; speedup 1.0000x reference)
//
#include <hip/hip_runtime.h>

#define D     512
#define NSUP  20          // n
#define NC    64          // classes
#define RES   25
#define BB    128
#define LAM   (20.0f/512.0f)

#define KT    32          // K tile
#define CPB   8           // classes per block in k_main
#define COLS  (CPB*NSUP)  // 160

// ---------------- Kernel 1: per-class B = A*G*A - 2A, A = inv(G + lam*I) ----
__global__ __launch_bounds__(256) void k_prep(const float* __restrict__ high,
                                              float* __restrict__ Bmat) {
    const int cls = blockIdx.x;
    const int t   = threadIdx.x;
    __shared__ float Hc[NSUP * 513];
    __shared__ float Gs[NSUP * NSUP];
    __shared__ float Aug[NSUP * 41];     // [G+lam I | I] padded
    __shared__ float Ts[NSUP * NSUP];
    __shared__ float fcol[NSUP];

    // stage class rows
    for (int i = t; i < NSUP * D; i += 256) {
        int r = i / D, c = i % D;
        Hc[r * 513 + c] = high[(cls * NSUP + r) * D + c];
    }
    __syncthreads();

    // Gram
    for (int e = t; e < NSUP * NSUP; e += 256) {
        int i = e / NSUP, j = e % NSUP;
        float s = 0.f;
        for (int k = 0; k < D; ++k) s += Hc[i * 513 + k] * Hc[j * 513 + k];
        Gs[e] = s;
    }
    __syncthreads();

    // augmented [G + lam I | I]
    for (int e = t; e < NSUP * 40; e += 256) {
        int r = e / 40, c = e % 40;
        float v;
        if (c < NSUP) v = Gs[r * NSUP + c] + (c == r ? LAM : 0.f);
        else          v = ((c - NSUP) == r) ? 1.f : 0.f;
        Aug[r * 41 + c] = v;
    }
    __syncthreads();

    // Gauss-Jordan (SPD -> no pivoting)
    for (int k = 0; k < NSUP; ++k) {
        float ip = 1.f / Aug[k * 41 + k];   // all threads read (broadcast)
        __syncthreads();
        if (t < 40) Aug[k * 41 + t] *= ip;
        __syncthreads();
        if (t < NSUP) fcol[t] = Aug[t * 41 + k];   // snapshot col k
        __syncthreads();
        for (int e = t; e < NSUP * 40; e += 256) {
            int r = e / 40, c = e % 40;
            if (r != k) Aug[r * 41 + c] -= fcol[r] * Aug[k * 41 + c];
        }
        __syncthreads();
    }

    // T = G @ A   (A = right half of Aug)
    for (int e = t; e < NSUP * NSUP; e += 256) {
        int i = e / NSUP, j = e % NSUP;
        float s = 0.f;
        for (int m = 0; m < NSUP; ++m) s += Gs[i * NSUP + m] * Aug[m * 41 + 20 + j];
        Ts[e] = s;
    }
    __syncthreads();
    // B = A @ T - 2A
    for (int e = t; e < NSUP * NSUP; e += 256) {
        int i = e / NSUP, j = e % NSUP;
        float s = 0.f;
        for (int m = 0; m < NSUP; ++m) s += Aug[i * 41 + 20 + m] * Ts[m * NSUP + j];
        Bmat[cls * 400 + e] = s - 2.f * Aug[i * 41 + 20 + j];
    }
}

// ---------------- Kernel 2: fused Y = X @ H^T (per class-group) + quad forms -
// grid: (8 class-groups, 128 batches), 256 threads
__global__ __launch_bounds__(256) void k_main(const float* __restrict__ x,
                                              const float* __restrict__ high,
                                              const float* __restrict__ Bmat,
                                              float* __restrict__ S) {
    const int cg = blockIdx.x;    // class group (8 classes)
    const int b  = blockIdx.y;
    const int t  = threadIdx.x;

    __shared__ float Xs[32 * (KT + 1)];    // 32 rows (25 real, rest zero)
    __shared__ float Hs[COLS * (KT + 1)];
    __shared__ float Ys[RES * 161];        // 25 x 160, padded
    __shared__ float Bs[CPB * 400];

    for (int i = t; i < CPB * 400; i += 256) Bs[i] = Bmat[cg * CPB * 400 + i];

    const int tr = t >> 5;     // 0..7  row-thread
    const int tc = t & 31;     // 0..31 col-thread
    float acc[4][5];
    #pragma unroll
    for (int a = 0; a < 4; ++a)
        #pragma unroll
        for (int bj = 0; bj < 5; ++bj) acc[a][bj] = 0.f;

    for (int kt = 0; kt < D; kt += KT) {
        for (int i = t; i < 32 * KT; i += 256) {
            int r = i >> 5, c = i & (KT - 1);
            Xs[r * (KT + 1) + c] = (r < RES) ? x[(b * RES + r) * D + kt + c] : 0.f;
        }
        for (int i = t; i < COLS * KT; i += 256) {
            int r = i >> 5, c = i & (KT - 1);
            Hs[r * (KT + 1) + c] = high[(cg * COLS + r) * D + kt + c];
        }
        __syncthreads();
        for (int k = 0; k < KT; ++k) {
            float av[4], bv[5];
            #pragma unroll
            for (int a = 0; a < 4; ++a)  av[a]  = Xs[(tr + 8 * a) * (KT + 1) + k];
            #pragma unroll
            for (int bj = 0; bj < 5; ++bj) bv[bj] = Hs[(tc + 32 * bj) * (KT + 1) + k];
            #pragma unroll
            for (int a = 0; a < 4; ++a)
                #pragma unroll
                for (int bj = 0; bj < 5; ++bj) acc[a][bj] += av[a] * bv[bj];
        }
        __syncthreads();
    }

    // write Y tile to LDS
    #pragma unroll
    for (int a = 0; a < 4; ++a) {
        int row = tr + 8 * a;
        if (row < RES) {
            #pragma unroll
            for (int bj = 0; bj < 5; ++bj) Ys[row * 161 + tc + 32 * bj] = acc[a][bj];
        }
    }
    __syncthreads();

    // quadratic forms: S[b, cg*8+ci] = sum_r y^T B y
    const int wave = t >> 6;
    const int lane = t & 63;
    const int half = lane >> 5;
    const int l32  = lane & 31;
    const int ci   = wave * 2 + half;   // 0..7 local class
    float s = 0.f;
    for (int r = 0; r < RES; ++r) {
        const float* yrow = &Ys[r * 161 + ci * NSUP];
        for (int e = l32; e < 400; e += 32) {
            int i = e / NSUP, j = e % NSUP;
            s += Bs[ci * 400 + e] * yrow[i] * yrow[j];
        }
    }
    #pragma unroll
    for (int off = 16; off > 0; off >>= 1) s += __shfl_xor(s, off, 32);
    if (l32 == 0) S[b * NC + cg * CPB + ci] = s;
}

// ---------------- Kernel 3: per-row min-max scale -----------------------------
__global__ __launch_bounds__(64) void k_minmax(const float* __restrict__ S,
                                               float* __restrict__ out) {
    const int b    = blockIdx.x;
    const int lane = threadIdx.x;
    float s  = S[b * NC + lane];
    float mn = s, mx = s;
    #pragma unroll
    for (int off = 32; off > 0; off >>= 1) {
        mn = fminf(mn, __shfl_xor(mn, off, 64));
        mx = fmaxf(mx, __shfl_xor(mx, off, 64));
    }
    // logits = -(const + a*S): minmax(logits) == (S_max - S)/(S_max - S_min)
    out[b * NC + lane] = (mx - s) / (mx - mn);
}

extern "C" void kernel_launch(void* const* d_in, const int* in_sizes, int n_in,
                              void* d_out, int out_size, void* d_ws, size_t ws_size,
                              hipStream_t stream) {
    const float* x    = (const float*)d_in[0];
    const float* high = (const float*)d_in[1];
    float* out  = (float*)d_out;
    float* Bmat = (float*)d_ws;                 // 64*400 f32 = 102,400 B
    float* S    = Bmat + NC * NSUP * NSUP;      // 128*64 f32 = 32,768 B

    k_prep  <<<NC, 256, 0, stream>>>(high, Bmat);
    k_main  <<<dim3(NC / CPB, BB), 256, 0, stream>>>(x, high, Bmat, S);
    k_minmax<<<BB, 64, 0, stream>>>(S, out);
}

// Round 3
// 216.872 us; speedup vs baseline: 1.3657x; 1.3657x over previous
//
#include <hip/hip_runtime.h>

#define D     512
#define NSUP  20
#define NC    64
#define RES   25
#define BB    128
#define LAM   (20.0f/512.0f)

#define KT    32
#define KSTR  36          // LDS row stride in floats: 16B-aligned, (9r+g)%8 injective
#define CPB   8
#define COLS  (CPB*NSUP)  // 160

// ---- Kernel 1: per-class  A=inv(G+lam I);  M=A+lam*A^2 (SPD);  M=LL^T;
// ----           Htilde = L^T @ H   (20 x 512)  ->  S = sum_r ||Htilde x_r||^2
__global__ __launch_bounds__(256) void k_prep(const float* __restrict__ high,
                                              float* __restrict__ Ht) {
    const int cls = blockIdx.x;
    const int t   = threadIdx.x;
    __shared__ float Hc[NSUP * 516];
    __shared__ float Gs[NSUP * NSUP];
    __shared__ float Aug[NSUP * 41];
    __shared__ float Ms[NSUP * NSUP];
    __shared__ float fcol[NSUP];

    // stage class rows (float4)
    for (int i = t; i < NSUP * (D / 4); i += 256) {
        int r = i >> 7, c4 = (i & 127) << 2;
        *(float4*)&Hc[r * 516 + c4] = *(const float4*)&high[(cls * NSUP + r) * D + c4];
    }
    __syncthreads();

    // Gram
    for (int e = t; e < NSUP * NSUP; e += 256) {
        int i = e / NSUP, j = e % NSUP;
        float s = 0.f;
        for (int k = 0; k < D; k += 4) {
            float4 a = *(float4*)&Hc[i * 516 + k];
            float4 b = *(float4*)&Hc[j * 516 + k];
            s += a.x * b.x + a.y * b.y + a.z * b.z + a.w * b.w;
        }
        Gs[e] = s;
    }
    __syncthreads();

    // augmented [G + lam I | I]
    for (int e = t; e < NSUP * 40; e += 256) {
        int r = e / 40, c = e % 40;
        float v;
        if (c < NSUP) v = Gs[r * NSUP + c] + (c == r ? LAM : 0.f);
        else          v = ((c - NSUP) == r) ? 1.f : 0.f;
        Aug[r * 41 + c] = v;
    }
    __syncthreads();

    // Gauss-Jordan (SPD, diagonally dominant -> no pivoting)
    for (int k = 0; k < NSUP; ++k) {
        float ip = 1.f / Aug[k * 41 + k];
        __syncthreads();
        if (t < 40) Aug[k * 41 + t] *= ip;
        __syncthreads();
        if (t < NSUP) fcol[t] = Aug[t * 41 + k];
        __syncthreads();
        for (int e = t; e < NSUP * 40; e += 256) {
            int r = e / 40, c = e % 40;
            if (r != k) Aug[r * 41 + c] -= fcol[r] * Aug[k * 41 + c];
        }
        __syncthreads();
    }

    // M = A + lam * A^2   (A = Aug[:,20:40])
    for (int e = t; e < NSUP * NSUP; e += 256) {
        int i = e / NSUP, j = e % NSUP;
        float s = 0.f;
        for (int m = 0; m < NSUP; ++m) s += Aug[i * 41 + 20 + m] * Aug[m * 41 + 20 + j];
        Ms[e] = Aug[i * 41 + 20 + j] + LAM * s;
    }
    __syncthreads();

    // Cholesky in-place (lower): M = L L^T
    for (int k = 0; k < NSUP; ++k) {
        if (t == 0) Ms[k * NSUP + k] = sqrtf(Ms[k * NSUP + k]);
        __syncthreads();
        if (t > k && t < NSUP) Ms[t * NSUP + k] /= Ms[k * NSUP + k];
        __syncthreads();
        for (int e = t; e < NSUP * NSUP; e += 256) {
            int i = e / NSUP, j = e % NSUP;
            if (j > k && j <= i) Ms[i * NSUP + j] -= Ms[i * NSUP + k] * Ms[j * NSUP + k];
        }
        __syncthreads();
    }

    // Htilde[i][k] = sum_{m>=i} L[m][i] * Hc[m][k]
    for (int e = t; e < NSUP * D; e += 256) {
        int i = e >> 9, k = e & 511;
        float s = 0.f;
        for (int m = i; m < NSUP; ++m) s += Ms[m * NSUP + i] * Hc[m * 516 + k];
        Ht[(cls * NSUP + i) * D + k] = s;
    }
}

// ---- Kernel 2: Z = X @ Htilde^T, S[b,c] = sum z^2 (pure GEMM + sq-acc epilogue)
// grid: (8 class-groups, 128 batches), 256 threads
__global__ __launch_bounds__(256, 5) void k_main(const float* __restrict__ x,
                                                 const float* __restrict__ Ht,
                                                 float* __restrict__ S) {
    const int cg = blockIdx.x;
    const int b  = blockIdx.y;
    const int t  = threadIdx.x;

    __shared__ float Xs[32 * KSTR];       // 4.6 KB (rows 25..31 zeroed)
    __shared__ float Hs[COLS * KSTR];     // 23.0 KB
    __shared__ float red[4][5][32];       // 2.5 KB
    __shared__ float colsum[COLS];        // 0.6 KB

    const int tr = t >> 5;     // 0..7
    const int tc = t & 31;     // 0..31
    float acc[4][5];
    #pragma unroll
    for (int a = 0; a < 4; ++a)
        #pragma unroll
        for (int bj = 0; bj < 5; ++bj) acc[a][bj] = 0.f;

    const int xr = t >> 3, xc4 = (t & 7) << 2;   // staging coords

    for (int kt = 0; kt < D; kt += KT) {
        float4 xv = make_float4(0.f, 0.f, 0.f, 0.f);
        if (xr < RES) xv = *(const float4*)&x[(b * RES + xr) * D + kt + xc4];
        *(float4*)&Xs[xr * KSTR + xc4] = xv;
        #pragma unroll
        for (int j = 0; j < 5; ++j) {
            int i  = t + j * 256;
            int hr = i >> 3, hc4 = (i & 7) << 2;
            *(float4*)&Hs[hr * KSTR + hc4] =
                *(const float4*)&Ht[(cg * COLS + hr) * D + kt + hc4];
        }
        __syncthreads();
        #pragma unroll
        for (int k4 = 0; k4 < KT; k4 += 4) {
            float4 xa[4], hb[5];
            #pragma unroll
            for (int a = 0; a < 4; ++a)  xa[a]  = *(float4*)&Xs[(tr + 8 * a) * KSTR + k4];
            #pragma unroll
            for (int bj = 0; bj < 5; ++bj) hb[bj] = *(float4*)&Hs[(tc + 32 * bj) * KSTR + k4];
            #pragma unroll
            for (int a = 0; a < 4; ++a)
                #pragma unroll
                for (int bj = 0; bj < 5; ++bj) {
                    acc[a][bj] += xa[a].x * hb[bj].x;
                    acc[a][bj] += xa[a].y * hb[bj].y;
                    acc[a][bj] += xa[a].z * hb[bj].z;
                    acc[a][bj] += xa[a].w * hb[bj].w;
                }
        }
        __syncthreads();
    }

    // per-thread column partials: sum over this thread's 4 rows of z^2
    const int wv = t >> 6, lane = t & 63;
    float sp[5];
    #pragma unroll
    for (int bj = 0; bj < 5; ++bj) {
        float s = 0.f;
        #pragma unroll
        for (int a = 0; a < 4; ++a) s += acc[a][bj] * acc[a][bj];
        s += __shfl_xor(s, 32);          // combine tr-pair within wave
        sp[bj] = s;
    }
    if (lane < 32) {
        #pragma unroll
        for (int bj = 0; bj < 5; ++bj) red[wv][bj][lane] = sp[bj];
    }
    __syncthreads();
    if (t < COLS) {                      // col = t = (t&31) + 32*(t>>5)
        float cs = 0.f;
        #pragma unroll
        for (int w = 0; w < 4; ++w) cs += red[w][t >> 5][t & 31];
        colsum[t] = cs;
    }
    __syncthreads();
    if (t < CPB) {
        float s = 0.f;
        #pragma unroll
        for (int i = 0; i < NSUP; ++i) s += colsum[t * NSUP + i];
        S[b * NC + cg * CPB + t] = s;
    }
}

// ---- Kernel 3: per-row min-max (S = -logits*25 + const  ->  (s-mn)/(mx-mn))
__global__ __launch_bounds__(64) void k_minmax(const float* __restrict__ S,
                                               float* __restrict__ out) {
    const int b    = blockIdx.x;
    const int lane = threadIdx.x;
    float s  = S[b * NC + lane];
    float mn = s, mx = s;
    #pragma unroll
    for (int off = 32; off > 0; off >>= 1) {
        mn = fminf(mn, __shfl_xor(mn, off, 64));
        mx = fmaxf(mx, __shfl_xor(mx, off, 64));
    }
    out[b * NC + lane] = (s - mn) / (mx - mn);
}

extern "C" void kernel_launch(void* const* d_in, const int* in_sizes, int n_in,
                              void* d_out, int out_size, void* d_ws, size_t ws_size,
                              hipStream_t stream) {
    const float* x    = (const float*)d_in[0];
    const float* high = (const float*)d_in[1];
    float* out = (float*)d_out;
    float* Ht  = (float*)d_ws;                    // 64*20*512 f32 = 2.62 MB
    float* S   = Ht + NC * NSUP * D;              // 128*64 f32 = 32 KB

    k_prep  <<<NC, 256, 0, stream>>>(high, Ht);
    k_main  <<<dim3(NC / CPB, BB), 256, 0, stream>>>(x, Ht, S);
    k_minmax<<<BB, 64, 0, stream>>>(S, out);
}

// Round 5
// 143.334 us; speedup vs baseline: 2.0663x; 1.5131x over previous
//
#include <hip/hip_runtime.h>

typedef __bf16 v8bf __attribute__((ext_vector_type(8)));
typedef float  v4f  __attribute__((ext_vector_type(4)));

#define D     512
#define NSUP  20
#define NC    64
#define RES   25
#define BB    128
#define LAM   (20.0f/512.0f)
#define KT    32
#define NKT   (D/KT)     // 16
#define CPB   8
#define COLS  160        // CPB*NSUP
#define NFRAG 10         // COLS/16
#define MFRAG 4          // 64 rows / 16

__device__ __forceinline__ ushort bf_hi(float v) {
    uint32_t b = __float_as_uint(v);
    return (ushort)((b + 0x7FFF + ((b >> 16) & 1)) >> 16);   // RNE
}
__device__ __forceinline__ float us2f(ushort u) {
    return __uint_as_float(((uint32_t)u) << 16);
}

// ---- Kernel 1: A=inv(G+lam I); M=A+lam*A^2 (SPD); M=LL^T; Htilde=L^T H ----
// ---- output: Hth/Htl = exact bf16 hi/lo split of Htilde (20x512 per class)
__global__ __launch_bounds__(256) void k_prep(const float* __restrict__ high,
                                              ushort* __restrict__ Hth,
                                              ushort* __restrict__ Htl) {
    const int cls = blockIdx.x;
    const int t   = threadIdx.x;
    __shared__ float Hc[NSUP * 516];
    __shared__ float Gs[NSUP * NSUP];
    __shared__ float Aug[NSUP * 41];
    __shared__ float Ms[NSUP * NSUP];
    __shared__ float fcol[NSUP];

    for (int i = t; i < NSUP * (D / 4); i += 256) {
        int r = i >> 7, c4 = (i & 127) << 2;
        *(float4*)&Hc[r * 516 + c4] = *(const float4*)&high[(cls * NSUP + r) * D + c4];
    }
    __syncthreads();

    for (int e = t; e < NSUP * NSUP; e += 256) {
        int i = e / NSUP, j = e % NSUP;
        float s = 0.f;
        for (int k = 0; k < D; k += 4) {
            float4 a = *(float4*)&Hc[i * 516 + k];
            float4 b = *(float4*)&Hc[j * 516 + k];
            s += a.x * b.x + a.y * b.y + a.z * b.z + a.w * b.w;
        }
        Gs[e] = s;
    }
    __syncthreads();

    for (int e = t; e < NSUP * 40; e += 256) {
        int r = e / 40, c = e % 40;
        float v;
        if (c < NSUP) v = Gs[r * NSUP + c] + (c == r ? LAM : 0.f);
        else          v = ((c - NSUP) == r) ? 1.f : 0.f;
        Aug[r * 41 + c] = v;
    }
    __syncthreads();

    for (int k = 0; k < NSUP; ++k) {
        float ip = 1.f / Aug[k * 41 + k];
        __syncthreads();
        if (t < 40) Aug[k * 41 + t] *= ip;
        __syncthreads();
        if (t < NSUP) fcol[t] = Aug[t * 41 + k];
        __syncthreads();
        for (int e = t; e < NSUP * 40; e += 256) {
            int r = e / 40, c = e % 40;
            if (r != k) Aug[r * 41 + c] -= fcol[r] * Aug[k * 41 + c];
        }
        __syncthreads();
    }

    // M = A + lam*A^2
    for (int e = t; e < NSUP * NSUP; e += 256) {
        int i = e / NSUP, j = e % NSUP;
        float s = 0.f;
        for (int m = 0; m < NSUP; ++m) s += Aug[i * 41 + 20 + m] * Aug[m * 41 + 20 + j];
        Ms[e] = Aug[i * 41 + 20 + j] + LAM * s;
    }
    __syncthreads();

    // Cholesky (lower)
    for (int k = 0; k < NSUP; ++k) {
        if (t == 0) Ms[k * NSUP + k] = sqrtf(Ms[k * NSUP + k]);
        __syncthreads();
        if (t > k && t < NSUP) Ms[t * NSUP + k] /= Ms[k * NSUP + k];
        __syncthreads();
        for (int e = t; e < NSUP * NSUP; e += 256) {
            int i = e / NSUP, j = e % NSUP;
            if (j > k && j <= i) Ms[i * NSUP + j] -= Ms[i * NSUP + k] * Ms[j * NSUP + k];
        }
        __syncthreads();
    }

    // Htilde[i][k] = sum_{m>=i} L[m][i]*Hc[m][k]; exact hi/lo bf16 split
    for (int e = t; e < NSUP * D; e += 256) {
        int i = e >> 9, k = e & 511;
        float s = 0.f;
        for (int m = i; m < NSUP; ++m) s += Ms[m * NSUP + i] * Hc[m * 516 + k];
        ushort h = bf_hi(s);
        float  r = s - us2f(h);
        ushort l = bf_hi(r);
        Hth[(cls * NSUP + i) * D + k] = h;
        Htl[(cls * NSUP + i) * D + k] = l;
    }
}

// ---- Kernel 2: Z = X @ Htilde^T via 4-pass hi/lo bf16 MFMA; S = sum z^2 ----
// grid (8 class-groups, 64 batch-pairs), 256 threads = 4 waves (2M x 2N)
__global__ __launch_bounds__(256, 2) void k_main(const float* __restrict__ x,
                                                 const ushort* __restrict__ Hth,
                                                 const ushort* __restrict__ Htl,
                                                 float* __restrict__ S) {
    const int cg = blockIdx.x, bp = blockIdx.y;
    const int t = threadIdx.x, lane = t & 63, wid = t >> 6;
    const int wm = wid >> 1, wn = wid & 1;

    // fragment-linear LDS: frag f, lane l -> 16B at [f*512 + l*8] (ushort units)
    __shared__ __align__(16) ushort XH[2][MFRAG * 512];
    __shared__ __align__(16) ushort XL[2][MFRAG * 512];
    __shared__ __align__(16) ushort HH[2][NFRAG * 512];
    __shared__ __align__(16) ushort HL[2][NFRAG * 512];
    __shared__ float colsum[2][COLS];

    v4f acc[2][5];
    #pragma unroll
    for (int a = 0; a < 2; ++a)
        #pragma unroll
        for (int b = 0; b < 5; ++b) acc[a][b] = (v4f){0.f, 0.f, 0.f, 0.f};

    // stage X tile (64 rows x KT), f32 -> exact hi/lo bf16, fragment-linear
    auto stageX = [&](int buf, int kt) {
        #pragma unroll
        for (int s2 = 0; s2 < 2; ++s2) {
            int g = t + 256 * s2;           // 0..511
            int p = g >> 3;                 // padded row 0..63
            int k0 = (g & 7) << 2;          // 0,4,...,28
            float4 v = make_float4(0.f, 0.f, 0.f, 0.f);
            int r = p & 31;
            if (r < RES)
                v = *(const float4*)&x[(((bp << 1) + (p >> 5)) * RES + r) * D + kt + k0];
            ushort4 hu, lu;
            {
                ushort h; float rr;
                h = bf_hi(v.x); rr = v.x - us2f(h); hu.x = h; lu.x = bf_hi(rr);
                h = bf_hi(v.y); rr = v.y - us2f(h); hu.y = h; lu.y = bf_hi(rr);
                h = bf_hi(v.z); rr = v.z - us2f(h); hu.z = h; lu.z = bf_hi(rr);
                h = bf_hi(v.w); rr = v.w - us2f(h); hu.w = h; lu.w = bf_hi(rr);
            }
            int m = p >> 4, i = p & 15, q = k0 >> 3, off = (k0 & 7);
            int base = m * 512 + (q * 16 + i) * 8 + off;
            *(ushort4*)&XH[buf][base] = hu;
            *(ushort4*)&XL[buf][base] = lu;
        }
    };

    // stage H frags: global_load_lds 16B, linear LDS dest, pre-swizzled source
    auto stageH = [&](int buf, int kt) {
        #pragma unroll
        for (int j = 0; j < 5; ++j) {
            int cid = wid * 5 + j;                       // 0..19
            int n = (cid < 10) ? cid : cid - 10;
            const ushort* src = (cid < 10) ? Hth : Htl;
            ushort* dst = (cid < 10) ? &HH[buf][n * 512] : &HL[buf][n * 512];
            int row = cg * COLS + n * 16 + (lane & 15);
            const ushort* gp = &src[row * D + kt + ((lane >> 4) << 3)];
            __builtin_amdgcn_global_load_lds(
                (const __attribute__((address_space(1))) void*)gp,
                (__attribute__((address_space(3))) void*)dst, 16, 0, 0);
        }
    };

    auto compute = [&](int buf) {
        v8bf ah[2], al[2];
        #pragma unroll
        for (int mf = 0; mf < 2; ++mf) {
            int f = wm * 2 + mf;
            ah[mf] = *(const v8bf*)&XH[buf][f * 512 + lane * 8];
            al[mf] = *(const v8bf*)&XL[buf][f * 512 + lane * 8];
        }
        #pragma unroll
        for (int nf = 0; nf < 5; ++nf) {
            int f = wn * 5 + nf;
            v8bf bh = *(const v8bf*)&HH[buf][f * 512 + lane * 8];
            v8bf bl = *(const v8bf*)&HL[buf][f * 512 + lane * 8];
            #pragma unroll
            for (int mf = 0; mf < 2; ++mf) {
                acc[mf][nf] = __builtin_amdgcn_mfma_f32_16x16x32_bf16(ah[mf], bh, acc[mf][nf], 0, 0, 0);
                acc[mf][nf] = __builtin_amdgcn_mfma_f32_16x16x32_bf16(ah[mf], bl, acc[mf][nf], 0, 0, 0);
                acc[mf][nf] = __builtin_amdgcn_mfma_f32_16x16x32_bf16(al[mf], bh, acc[mf][nf], 0, 0, 0);
                acc[mf][nf] = __builtin_amdgcn_mfma_f32_16x16x32_bf16(al[mf], bl, acc[mf][nf], 0, 0, 0);
            }
        }
    };

    stageX(0, 0);
    stageH(0, 0);
    __syncthreads();
    for (int step = 0; step < NKT; ++step) {
        int cur = step & 1;
        if (step + 1 < NKT) {
            stageH(cur ^ 1, (step + 1) * KT);
            stageX(cur ^ 1, (step + 1) * KT);
        }
        compute(cur);
        __syncthreads();
    }

    // z^2 column sums; C-frag: col = lane&15, row = 4*(lane>>4)+j
    #pragma unroll
    for (int nf = 0; nf < 5; ++nf) {
        float part = 0.f;
        #pragma unroll
        for (int mf = 0; mf < 2; ++mf)
            #pragma unroll
            for (int j = 0; j < 4; ++j) part += acc[mf][nf][j] * acc[mf][nf][j];
        part += __shfl_xor(part, 16);
        part += __shfl_xor(part, 32);
        if ((lane >> 4) == 0) colsum[wm][wn * 80 + nf * 16 + lane] = part;
    }
    __syncthreads();
    if (t < 16) {
        int b = t >> 3, c = t & 7;
        float s = 0.f;
        #pragma unroll
        for (int i = 0; i < NSUP; ++i) s += colsum[b][c * 20 + i];
        S[((bp << 1) + b) * NC + cg * CPB + c] = s;
    }
}

// ---- Kernel 3: per-row min-max ----
__global__ __launch_bounds__(64) void k_minmax(const float* __restrict__ S,
                                               float* __restrict__ out) {
    const int b    = blockIdx.x;
    const int lane = threadIdx.x;
    float s  = S[b * NC + lane];
    float mn = s, mx = s;
    #pragma unroll
    for (int off = 32; off > 0; off >>= 1) {
        mn = fminf(mn, __shfl_xor(mn, off, 64));
        mx = fmaxf(mx, __shfl_xor(mx, off, 64));
    }
    out[b * NC + lane] = (s - mn) / (mx - mn);
}

extern "C" void kernel_launch(void* const* d_in, const int* in_sizes, int n_in,
                              void* d_out, int out_size, void* d_ws, size_t ws_size,
                              hipStream_t stream) {
    const float* x    = (const float*)d_in[0];
    const float* high = (const float*)d_in[1];
    float* out = (float*)d_out;

    ushort* Hth = (ushort*)d_ws;                       // 64*20*512 u16 = 1.31 MB
    ushort* Htl = Hth + NC * NSUP * D;                 // 1.31 MB
    float*  S   = (float*)(Htl + NC * NSUP * D);       // 128*64 f32 = 32 KB

    k_prep  <<<NC, 256, 0, stream>>>(high, Hth, Htl);
    k_main  <<<dim3(CPB, BB / 2), 256, 0, stream>>>(x, Hth, Htl, S);
    k_minmax<<<BB, 64, 0, stream>>>(S, out);
}